// Round 1
// baseline (29316.800 us; speedup 1.0000x reference)
//
#include <hip/hip_runtime.h>
#include <stdint.h>

typedef __attribute__((ext_vector_type(8))) short short8;
typedef __attribute__((ext_vector_type(4))) float f32x4;

#define MFMA16(a, b, c) __builtin_amdgcn_mfma_f32_16x16x32_bf16((a), (b), (c), 0, 0, 0)

__device__ __forceinline__ unsigned short f2bf(float f) {
  unsigned u = __float_as_uint(f);
  u = (u + 0x7FFFu + ((u >> 16) & 1u)) >> 16;   // RNE
  return (unsigned short)u;
}
__device__ __forceinline__ float bf2f(unsigned short u) {
  return __uint_as_float(((unsigned)u) << 16);
}

// ---------------- prep: fp32 -> bf16 conversion ----------------
__global__ void k_cvt(const float* __restrict__ src, unsigned short* __restrict__ dst, int n4) {
  int stride = gridDim.x * blockDim.x;
  for (int i = blockIdx.x * blockDim.x + threadIdx.x; i < n4; i += stride) {
    float4 v = reinterpret_cast<const float4*>(src)[i];
    ushort4 o;
    o.x = f2bf(v.x); o.y = f2bf(v.y); o.z = f2bf(v.z); o.w = f2bf(v.w);
    reinterpret_cast<ushort4*>(dst)[i] = o;
  }
}

__global__ void k_bias(const float* __restrict__ a, const float* __restrict__ b,
                       float* __restrict__ o, int n) {
  int i = blockIdx.x * blockDim.x + threadIdx.x;
  if (i < n) o[i] = a[i] + b[i];
}

// ---------------- xp GEMM: out[r][n] = sum_k A[r][k]*W[n][k] + bias[n] ----------------
// A: bf16, K=1024, row r -> (t = r/64, b = r%64).  mode 0: A row = b*512+t (x layout)
//                                                  mode 1: A row = r      (out0 layout)
// W: bf16 (4096,1024) row-major. out: bf16 (M,4096), M = 32768.
__global__ __launch_bounds__(256) void k_gemm(
    const unsigned short* __restrict__ A,
    const unsigned short* __restrict__ W,
    const float* __restrict__ bias,
    unsigned short* __restrict__ out,
    int mode) {
  const int tid = threadIdx.x, l = tid & 63, wv = tid >> 6;
  const int wm = wv >> 1, wn = wv & 1;
  const int tm = blockIdx.x >> 5, tn = blockIdx.x & 31;   // 256 x 32 tiles of 128x128
  const int m_base = tm * 128 + wm * 64;
  const int n_base = tn * 128 + wn * 64;
  const int lr = l & 15, k8 = (l >> 4) << 3;

  size_t a_off[4], b_off[4];
#pragma unroll
  for (int i = 0; i < 4; ++i) {
    int r = m_base + i * 16 + lr;
    int ar = mode ? r : (((r & 63) << 9) + (r >> 6));
    a_off[i] = ((size_t)ar << 10) + k8;
    int nr = n_base + i * 16 + lr;
    b_off[i] = ((size_t)nr << 10) + k8;
  }
  f32x4 acc[4][4] = {};
#pragma unroll 2
  for (int k0 = 0; k0 < 1024; k0 += 32) {
    short8 a[4], b[4];
#pragma unroll
    for (int i = 0; i < 4; ++i) a[i] = *reinterpret_cast<const short8*>(A + a_off[i] + k0);
#pragma unroll
    for (int j = 0; j < 4; ++j) b[j] = *reinterpret_cast<const short8*>(W + b_off[j] + k0);
#pragma unroll
    for (int i = 0; i < 4; ++i)
#pragma unroll
      for (int j = 0; j < 4; ++j) acc[i][j] = MFMA16(a[i], b[j], acc[i][j]);
  }
  // epilogue: D row = (l>>4)*4+q, col = l&15 (measured C/D layout)
  const int oq = (l >> 4) << 2, oc = l & 15;
#pragma unroll
  for (int j = 0; j < 4; ++j) {
    int col = n_base + j * 16 + oc;
    float bs = bias[col];
#pragma unroll
    for (int i = 0; i < 4; ++i) {
      int r0 = m_base + i * 16 + oq;
#pragma unroll
      for (int q = 0; q < 4; ++q)
        out[((size_t)(r0 + q) << 12) + col] = f2bf(acc[i][j][q] + bs);
    }
  }
}

// ---------------- persistent LSTM recurrence ----------------
// grid = 256 WGs x 256 threads. Group g = wg>>7 handles batches [g*32, g*32+32).
// WG w-in-group owns h-cols [w*8, w*8+8) -> 32 gathered gate cols (i,f,g,o x 8).
// W_hh slice (32 rows x 1024) lives swizzled in LDS for all 512 steps.
// h double-buffered bf16 in global; flag barrier per step within each group.
__global__ __launch_bounds__(256) void k_rec(
    const unsigned short* __restrict__ xp,     // (S, B, 4096) bf16, includes b_ih+b_hh
    const unsigned short* __restrict__ Whh,    // (4096, 1024) bf16
    unsigned short* __restrict__ hbuf,         // 2 x (64 x 1024) bf16
    int* __restrict__ flags,                   // per group: +g*512 (128 flags, release at +256)
    unsigned short* __restrict__ out_bf,       // layer0: (S,B,1024) bf16, else null
    float* __restrict__ out_f32,               // layer1: (B,S,1024) fp32 (d_out), else null
    float* __restrict__ hn, float* __restrict__ cn) {
  extern __shared__ char smem[];               // [0,64K) W swizzled, [64K,64K+4K) gates f32
  float* gates = (float*)(smem + 65536);

  const int tid = threadIdx.x;
  const int l = tid & 63, wv = tid >> 6;
  const int wg = blockIdx.x;
  const int g = wg >> 7;
  const int w = wg & 127;
  const int j0 = w << 3;

  int* gflags = flags + g * 512;
  int* grel = gflags + 256;

  // stage W slice into LDS, XOR-swizzled: byte = lr*2048 + ((k*2) ^ ((lr&7)<<4))
  for (int idx = tid; idx < 4096; idx += 256) {
    int lrow = idx >> 7, c = idx & 127;
    int wr = ((lrow >> 3) << 10) + j0 + (lrow & 7);
    uint4 v = *reinterpret_cast<const uint4*>(Whh + ((size_t)wr << 10) + (c << 3));
    int dst = (lrow << 11) + ((c << 4) ^ ((lrow & 7) << 4));
    *reinterpret_cast<uint4*>(smem + dst) = v;
  }

  const int wm = wv >> 1, nt = wv & 1;
  const int lr16 = l & 15, k8 = (l >> 4) << 3;
  const int brow = (nt << 4) + lr16;
  const int bswz = (brow & 7) << 4;
  const int bbase = brow << 11;
  const int arow = (g << 5) + (wm << 4) + lr16;   // batch row for a-frag

  const int b_l = tid >> 3, jj = tid & 7;
  const int b_g = (g << 5) + b_l;
  const int ecol = j0 + jj;

  float c_state = 0.f;
  __syncthreads();

  for (int t = 0; t < 512; ++t) {
    // xp loads issued early (no dependence on h)
    const unsigned short* xpt = xp + ((size_t)t << 18) + ((size_t)b_g << 12) + ecol;
    float gi = bf2f(xpt[0]);
    float gf = bf2f(xpt[1024]);
    float gg = bf2f(xpt[2048]);
    float go = bf2f(xpt[3072]);

    if (t > 0) {
      const unsigned short* aptr = hbuf + ((t & 1) << 16) + ((size_t)arow << 10) + k8;
      f32x4 acc0 = {0.f, 0.f, 0.f, 0.f}, acc1 = {0.f, 0.f, 0.f, 0.f};
#pragma unroll
      for (int kk = 0; kk < 32; kk += 2) {
        short8 a0 = *reinterpret_cast<const short8*>(aptr + (kk << 5));
        int kb0 = ((kk << 5) + k8) << 1;
        short8 b0 = *reinterpret_cast<const short8*>(smem + bbase + (kb0 ^ bswz));
        acc0 = MFMA16(a0, b0, acc0);
        short8 a1 = *reinterpret_cast<const short8*>(aptr + (kk << 5) + 32);
        short8 b1 = *reinterpret_cast<const short8*>(smem + bbase + ((kb0 + 64) ^ bswz));
        acc1 = MFMA16(a1, b1, acc1);
      }
      f32x4 r = acc0 + acc1;
      int gcol = (nt << 4) + lr16;
      int grow = (wm << 4) + ((l >> 4) << 2);
      gates[(grow + 0) * 32 + gcol] = r[0];
      gates[(grow + 1) * 32 + gcol] = r[1];
      gates[(grow + 2) * 32 + gcol] = r[2];
      gates[(grow + 3) * 32 + gcol] = r[3];
    }
    __syncthreads();

    if (t > 0) {
      gi += gates[b_l * 32 + jj];
      gf += gates[b_l * 32 + 8 + jj];
      gg += gates[b_l * 32 + 16 + jj];
      go += gates[b_l * 32 + 24 + jj];
    }
    float is = 1.f / (1.f + expf(-gi));
    float fs = 1.f / (1.f + expf(-gf));
    float gt = tanhf(gg);
    float os = 1.f / (1.f + expf(-go));
    c_state = fs * c_state + is * gt;
    float hval = os * tanhf(c_state);
    unsigned short h16 = f2bf(hval);

    hbuf[(((t + 1) & 1) << 16) + ((size_t)b_g << 10) + ecol] = h16;
    if (out_bf) {
      out_bf[((((size_t)t << 6) + b_g) << 10) + ecol] = h16;
    } else {
      out_f32[((((size_t)b_g << 9) + t) << 10) + ecol] = hval;
    }
    if (t == 511) {
      hn[((size_t)b_g << 10) + ecol] = hval;
      cn[((size_t)b_g << 10) + ecol] = c_state;
    }

    // ---- group barrier (flag + leader release, monotonic counters) ----
    if (t != 511) {
      __syncthreads();
      if (tid == 0) {
        __threadfence();
        __hip_atomic_store(&gflags[w], t + 1, __ATOMIC_RELEASE, __HIP_MEMORY_SCOPE_AGENT);
      }
      if (w == 0) {
        if (tid < 64) {
          for (;;) {
            int v0 = __hip_atomic_load(&gflags[tid << 1], __ATOMIC_ACQUIRE, __HIP_MEMORY_SCOPE_AGENT);
            int v1 = __hip_atomic_load(&gflags[(tid << 1) + 1], __ATOMIC_ACQUIRE, __HIP_MEMORY_SCOPE_AGENT);
            if (__all(v0 > t && v1 > t)) break;
            __builtin_amdgcn_s_sleep(1);
          }
          if (tid == 0)
            __hip_atomic_store(grel, t + 1, __ATOMIC_RELEASE, __HIP_MEMORY_SCOPE_AGENT);
        }
      } else if (tid == 0) {
        while (__hip_atomic_load(grel, __ATOMIC_ACQUIRE, __HIP_MEMORY_SCOPE_AGENT) <= t) {
          __builtin_amdgcn_s_sleep(1);
        }
      }
      __syncthreads();
    }
  }
}

// ---------------- launch ----------------
extern "C" void kernel_launch(void* const* d_in, const int* in_sizes, int n_in,
                              void* d_out, int out_size, void* d_ws, size_t ws_size,
                              hipStream_t stream) {
  (void)in_sizes; (void)n_in; (void)out_size; (void)ws_size;
  const float* x    = (const float*)d_in[0];
  const float* Wih0 = (const float*)d_in[1];
  const float* bih0 = (const float*)d_in[2];
  const float* Whh0 = (const float*)d_in[3];
  const float* bhh0 = (const float*)d_in[4];
  const float* Wih1 = (const float*)d_in[5];
  const float* bih1 = (const float*)d_in[6];
  const float* Whh1 = (const float*)d_in[7];
  const float* bhh1 = (const float*)d_in[8];
  float* dout = (float*)d_out;

  char* ws = (char*)d_ws;
  int*            flags = (int*)ws;                          // 8 KB
  unsigned short* hbuf  = (unsigned short*)(ws + 8192);      // 256 KB
  float*          bias0 = (float*)(ws + 270336);             // 16 KB
  float*          bias1 = (float*)(ws + 286720);             // 16 KB
  unsigned short* wbf   = (unsigned short*)(ws + 303104);    // 32 MB: ih0,hh0,ih1,hh1
  unsigned short* xbf   = wbf + 16777216;                    // 64 MB
  unsigned short* out0  = xbf + 33554432;                    // 64 MB
  unsigned short* xpb   = out0 + 33554432;                   // 256 MB (shared both layers)

  hipMemsetAsync(flags, 0, 8192, stream);

  k_cvt<<<1024, 256, 0, stream>>>(x, xbf, 33554432 / 4);
  k_cvt<<<256, 256, 0, stream>>>(Wih0, wbf + 0,        4194304 / 4);
  k_cvt<<<256, 256, 0, stream>>>(Whh0, wbf + 4194304,  4194304 / 4);
  k_cvt<<<256, 256, 0, stream>>>(Wih1, wbf + 8388608,  4194304 / 4);
  k_cvt<<<256, 256, 0, stream>>>(Whh1, wbf + 12582912, 4194304 / 4);
  k_bias<<<16, 256, 0, stream>>>(bih0, bhh0, bias0, 4096);
  k_bias<<<16, 256, 0, stream>>>(bih1, bhh1, bias1, 4096);

  hipFuncSetAttribute((const void*)k_rec, hipFuncAttributeMaxDynamicSharedMemorySize, 69632);

  float* hn = dout + 33554432;
  float* cn = dout + 33554432 + 131072;

  // layer 0
  k_gemm<<<8192, 256, 0, stream>>>(xbf, wbf + 0, bias0, xpb, 0);
  k_rec<<<256, 256, 69632, stream>>>(xpb, wbf + 4194304, hbuf, flags,
                                     out0, nullptr, hn, cn);
  // layer 1
  k_gemm<<<8192, 256, 0, stream>>>(out0, wbf + 8388608, bias1, xpb, 1);
  k_rec<<<256, 256, 69632, stream>>>(xpb, wbf + 12582912, hbuf, flags + 1024,
                                     nullptr, dout, hn + 65536, cn + 65536);
}

// Round 2
// 12976.495 us; speedup vs baseline: 2.2592x; 2.2592x over previous
//
#include <hip/hip_runtime.h>
#include <stdint.h>

typedef __attribute__((ext_vector_type(8))) short short8;
typedef __attribute__((ext_vector_type(4))) float f32x4;

#define MFMA16(a, b, c) __builtin_amdgcn_mfma_f32_16x16x32_bf16((a), (b), (c), 0, 0, 0)
#define AL(p) __hip_atomic_load((p), __ATOMIC_RELAXED, __HIP_MEMORY_SCOPE_AGENT)
#define AS(p, v) __hip_atomic_store((p), (v), __ATOMIC_RELAXED, __HIP_MEMORY_SCOPE_AGENT)

__device__ __forceinline__ unsigned short f2bf(float f) {
  unsigned u = __float_as_uint(f);
  u = (u + 0x7FFFu + ((u >> 16) & 1u)) >> 16;   // RNE
  return (unsigned short)u;
}
__device__ __forceinline__ float bf2f(unsigned short u) {
  return __uint_as_float(((unsigned)u) << 16);
}

// ---------------- prep: fp32 -> bf16 conversion ----------------
__global__ void k_cvt(const float* __restrict__ src, unsigned short* __restrict__ dst, int n4) {
  int stride = gridDim.x * blockDim.x;
  for (int i = blockIdx.x * blockDim.x + threadIdx.x; i < n4; i += stride) {
    float4 v = reinterpret_cast<const float4*>(src)[i];
    ushort4 o;
    o.x = f2bf(v.x); o.y = f2bf(v.y); o.z = f2bf(v.z); o.w = f2bf(v.w);
    reinterpret_cast<ushort4*>(dst)[i] = o;
  }
}

__global__ void k_bias(const float* __restrict__ a, const float* __restrict__ b,
                       float* __restrict__ o, int n) {
  int i = blockIdx.x * blockDim.x + threadIdx.x;
  if (i < n) o[i] = a[i] + b[i];
}

// ---------------- xp GEMM: out[r][n] = sum_k A[r][k]*W[n][k] + bias[n] ----------------
__global__ __launch_bounds__(256) void k_gemm(
    const unsigned short* __restrict__ A,
    const unsigned short* __restrict__ W,
    const float* __restrict__ bias,
    unsigned short* __restrict__ out,
    int mode) {
  const int tid = threadIdx.x, l = tid & 63, wv = tid >> 6;
  const int wm = wv >> 1, wn = wv & 1;
  const int tm = blockIdx.x >> 5, tn = blockIdx.x & 31;   // 256 x 32 tiles of 128x128
  const int m_base = tm * 128 + wm * 64;
  const int n_base = tn * 128 + wn * 64;
  const int lr = l & 15, k8 = (l >> 4) << 3;

  size_t a_off[4], b_off[4];
#pragma unroll
  for (int i = 0; i < 4; ++i) {
    int r = m_base + i * 16 + lr;
    int ar = mode ? r : (((r & 63) << 9) + (r >> 6));
    a_off[i] = ((size_t)ar << 10) + k8;
    int nr = n_base + i * 16 + lr;
    b_off[i] = ((size_t)nr << 10) + k8;
  }
  f32x4 acc[4][4] = {};
#pragma unroll 2
  for (int k0 = 0; k0 < 1024; k0 += 32) {
    short8 a[4], b[4];
#pragma unroll
    for (int i = 0; i < 4; ++i) a[i] = *reinterpret_cast<const short8*>(A + a_off[i] + k0);
#pragma unroll
    for (int j = 0; j < 4; ++j) b[j] = *reinterpret_cast<const short8*>(W + b_off[j] + k0);
#pragma unroll
    for (int i = 0; i < 4; ++i)
#pragma unroll
      for (int j = 0; j < 4; ++j) acc[i][j] = MFMA16(a[i], b[j], acc[i][j]);
  }
  const int oq = (l >> 4) << 2, oc = l & 15;
#pragma unroll
  for (int j = 0; j < 4; ++j) {
    int col = n_base + j * 16 + oc;
    float bs = bias[col];
#pragma unroll
    for (int i = 0; i < 4; ++i) {
      int r0 = m_base + i * 16 + oq;
#pragma unroll
      for (int q = 0; q < 4; ++q)
        out[((size_t)(r0 + q) << 12) + col] = f2bf(acc[i][j][q] + bs);
    }
  }
}

// ---------------- persistent LSTM recurrence ----------------
// grid = 256 WGs x 256 threads. Group g = wg>>7 handles batches [g*32, g*32+32).
// WG w owns h-cols [w*8, w*8+8). W_hh slice (32 rows x 1024) swizzled in LDS.
// All cross-WG traffic (h, flags) via RELAXED agent atomics (sc1, no wbl2/inv).
__global__ __launch_bounds__(256) void k_rec(
    const unsigned short* __restrict__ xp,     // (S, B, 4096) bf16, includes b_ih+b_hh
    const unsigned short* __restrict__ Whh,    // (4096, 1024) bf16
    unsigned short* __restrict__ hbuf,         // 2 x (64 x 1024) bf16
    int* __restrict__ flags,                   // per group: +g*512 (128 flags, release at +256)
    unsigned short* __restrict__ out_bf,       // layer0: (S,B,1024) bf16, else null
    float* __restrict__ out_f32,               // layer1: (B,S,1024) fp32 (d_out), else null
    float* __restrict__ hn, float* __restrict__ cn) {
  extern __shared__ char smem[];               // [0,64K) W swizzled, [64K,64K+4K) gates f32
  float* gates = (float*)(smem + 65536);

  const int tid = threadIdx.x;
  const int l = tid & 63, wv = tid >> 6;
  const int wg = blockIdx.x;
  const int g = wg >> 7;
  const int w = wg & 127;
  const int j0 = w << 3;

  int* gflags = flags + g * 512;
  int* grel = gflags + 256;

  // stage W slice into LDS, XOR-swizzled: byte = lr*2048 + ((k*2) ^ ((lr&7)<<4))
  for (int idx = tid; idx < 4096; idx += 256) {
    int lrow = idx >> 7, c = idx & 127;
    int wr = ((lrow >> 3) << 10) + j0 + (lrow & 7);
    uint4 v = *reinterpret_cast<const uint4*>(Whh + ((size_t)wr << 10) + (c << 3));
    int dst = (lrow << 11) + ((c << 4) ^ ((lrow & 7) << 4));
    *reinterpret_cast<uint4*>(smem + dst) = v;
  }

  const int wm = wv >> 1, nt = wv & 1;
  const int lr16 = l & 15, k8 = (l >> 4) << 3;
  const int brow = (nt << 4) + lr16;
  const int bswz = (brow & 7) << 4;
  const int bbase = brow << 11;
  const int arow = (g << 5) + (wm << 4) + lr16;   // batch row for a-frag

  // elementwise mapping: first 128 threads, 2 adjacent cols each
  const bool ew = tid < 128;
  const int b_l = tid >> 2;            // 0..31
  const int jj2 = (tid & 3) << 1;      // 0,2,4,6
  const int b_g = (g << 5) + b_l;
  const int ecol = j0 + jj2;

  float cs0 = 0.f, cs1 = 0.f;
  __syncthreads();

  typedef union { unsigned long long q[2]; short8 s; } afrag_u;

  for (int t = 0; t < 512; ++t) {
    // xp loads issued early (no dependence on h); plain loads (producer kernel ended)
    float gi0 = 0.f, gi1 = 0.f, gf0 = 0.f, gf1 = 0.f;
    float gg0 = 0.f, gg1 = 0.f, go0 = 0.f, go1 = 0.f;
    if (ew) {
      const unsigned* xpu = reinterpret_cast<const unsigned*>(
          xp + ((size_t)t << 18) + ((size_t)b_g << 12) + ecol);
      unsigned ui = xpu[0];
      unsigned uf = xpu[512];
      unsigned ug = xpu[1024];
      unsigned uo = xpu[1536];
      gi0 = bf2f((unsigned short)ui); gi1 = bf2f((unsigned short)(ui >> 16));
      gf0 = bf2f((unsigned short)uf); gf1 = bf2f((unsigned short)(uf >> 16));
      gg0 = bf2f((unsigned short)ug); gg1 = bf2f((unsigned short)(ug >> 16));
      go0 = bf2f((unsigned short)uo); go1 = bf2f((unsigned short)(uo >> 16));
    }

    if (t > 0) {
      const unsigned long long* aq = reinterpret_cast<const unsigned long long*>(
          hbuf + ((t & 1) << 16) + ((size_t)arow << 10) + k8);
      f32x4 acc0 = {0.f, 0.f, 0.f, 0.f}, acc1 = {0.f, 0.f, 0.f, 0.f};
#pragma unroll
      for (int kk = 0; kk < 32; kk += 2) {
        afrag_u a0, a1;
        a0.q[0] = AL(aq + (kk << 3));
        a0.q[1] = AL(aq + (kk << 3) + 1);
        a1.q[0] = AL(aq + (kk << 3) + 8);
        a1.q[1] = AL(aq + (kk << 3) + 9);
        int kb0 = ((kk << 5) + k8) << 1;
        short8 b0 = *reinterpret_cast<const short8*>(smem + bbase + (kb0 ^ bswz));
        short8 b1 = *reinterpret_cast<const short8*>(smem + bbase + ((kb0 + 64) ^ bswz));
        acc0 = MFMA16(a0.s, b0, acc0);
        acc1 = MFMA16(a1.s, b1, acc1);
      }
      f32x4 r = acc0 + acc1;
      int gcol = (nt << 4) + lr16;
      int grow = (wm << 4) + ((l >> 4) << 2);
      gates[(grow + 0) * 32 + gcol] = r[0];
      gates[(grow + 1) * 32 + gcol] = r[1];
      gates[(grow + 2) * 32 + gcol] = r[2];
      gates[(grow + 3) * 32 + gcol] = r[3];
    }
    __syncthreads();

    if (ew) {
      if (t > 0) {
        const float2* gr = reinterpret_cast<const float2*>(&gates[b_l * 32]);
        float2 ai = gr[jj2 >> 1];
        float2 af = gr[(8 + jj2) >> 1];
        float2 ag = gr[(16 + jj2) >> 1];
        float2 ao = gr[(24 + jj2) >> 1];
        gi0 += ai.x; gi1 += ai.y;
        gf0 += af.x; gf1 += af.y;
        gg0 += ag.x; gg1 += ag.y;
        go0 += ao.x; go1 += ao.y;
      }
      float i0 = 1.f / (1.f + expf(-gi0)), i1 = 1.f / (1.f + expf(-gi1));
      float f0 = 1.f / (1.f + expf(-gf0)), f1 = 1.f / (1.f + expf(-gf1));
      float g0 = tanhf(gg0), g1 = tanhf(gg1);
      float o0 = 1.f / (1.f + expf(-go0)), o1 = 1.f / (1.f + expf(-go1));
      cs0 = f0 * cs0 + i0 * g0;
      cs1 = f1 * cs1 + i1 * g1;
      float h0v = o0 * tanhf(cs0);
      float h1v = o1 * tanhf(cs1);
      unsigned hw = (unsigned)f2bf(h0v) | ((unsigned)f2bf(h1v) << 16);

      AS(reinterpret_cast<unsigned*>(
             hbuf + (((t + 1) & 1) << 16) + ((size_t)b_g << 10) + ecol), hw);
      if (out_bf) {
        *reinterpret_cast<unsigned*>(
            out_bf + ((((size_t)t << 6) + b_g) << 10) + ecol) = hw;
      } else {
        *reinterpret_cast<float2*>(
            out_f32 + ((((size_t)b_g << 9) + t) << 10) + ecol) = make_float2(h0v, h1v);
      }
      if (t == 511) {
        *reinterpret_cast<float2*>(hn + ((size_t)b_g << 10) + ecol) = make_float2(h0v, h1v);
        *reinterpret_cast<float2*>(cn + ((size_t)b_g << 10) + ecol) = make_float2(cs0, cs1);
      }
    }

    // ---- group barrier: drain own stores, arrive (sc1), leader release (sc1) ----
    if (t != 511) {
      asm volatile("s_waitcnt vmcnt(0)" ::: "memory");
      __syncthreads();   // all threads' h stores complete (sc1 -> at MALL)
      if (tid == 0)
        AS(&gflags[w], t + 1);
      if (w == 0) {
        if (tid < 64) {
          for (;;) {
            int v0 = AL(&gflags[tid << 1]);
            int v1 = AL(&gflags[(tid << 1) + 1]);
            if (__all(v0 > t && v1 > t)) break;
            __builtin_amdgcn_s_sleep(1);
          }
          if (tid == 0)
            AS(grel, t + 1);
        }
      } else if (tid == 0) {
        while (AL(grel) <= t) __builtin_amdgcn_s_sleep(1);
      }
      __syncthreads();
    }
  }
}

// ---------------- launch ----------------
extern "C" void kernel_launch(void* const* d_in, const int* in_sizes, int n_in,
                              void* d_out, int out_size, void* d_ws, size_t ws_size,
                              hipStream_t stream) {
  (void)in_sizes; (void)n_in; (void)out_size; (void)ws_size;
  const float* x    = (const float*)d_in[0];
  const float* Wih0 = (const float*)d_in[1];
  const float* bih0 = (const float*)d_in[2];
  const float* Whh0 = (const float*)d_in[3];
  const float* bhh0 = (const float*)d_in[4];
  const float* Wih1 = (const float*)d_in[5];
  const float* bih1 = (const float*)d_in[6];
  const float* Whh1 = (const float*)d_in[7];
  const float* bhh1 = (const float*)d_in[8];
  float* dout = (float*)d_out;

  char* ws = (char*)d_ws;
  int*            flags = (int*)ws;                          // 8 KB
  unsigned short* hbuf  = (unsigned short*)(ws + 8192);      // 256 KB
  float*          bias0 = (float*)(ws + 270336);             // 16 KB
  float*          bias1 = (float*)(ws + 286720);             // 16 KB
  unsigned short* wbf   = (unsigned short*)(ws + 303104);    // 32 MB: ih0,hh0,ih1,hh1
  unsigned short* xbf   = wbf + 16777216;                    // 64 MB
  unsigned short* out0  = xbf + 33554432;                    // 64 MB
  unsigned short* xpb   = out0 + 33554432;                   // 256 MB (shared both layers)

  hipMemsetAsync(flags, 0, 8192, stream);

  k_cvt<<<1024, 256, 0, stream>>>(x, xbf, 33554432 / 4);
  k_cvt<<<256, 256, 0, stream>>>(Wih0, wbf + 0,        4194304 / 4);
  k_cvt<<<256, 256, 0, stream>>>(Whh0, wbf + 4194304,  4194304 / 4);
  k_cvt<<<256, 256, 0, stream>>>(Wih1, wbf + 8388608,  4194304 / 4);
  k_cvt<<<256, 256, 0, stream>>>(Whh1, wbf + 12582912, 4194304 / 4);
  k_bias<<<16, 256, 0, stream>>>(bih0, bhh0, bias0, 4096);
  k_bias<<<16, 256, 0, stream>>>(bih1, bhh1, bias1, 4096);

  hipFuncSetAttribute((const void*)k_rec, hipFuncAttributeMaxDynamicSharedMemorySize, 69632);

  float* hn = dout + 33554432;
  float* cn = dout + 33554432 + 131072;

  // layer 0
  k_gemm<<<8192, 256, 0, stream>>>(xbf, wbf + 0, bias0, xpb, 0);
  k_rec<<<256, 256, 69632, stream>>>(xpb, wbf + 4194304, hbuf, flags,
                                     out0, nullptr, hn, cn);
  // layer 1
  k_gemm<<<8192, 256, 0, stream>>>(out0, wbf + 8388608, bias1, xpb, 1);
  k_rec<<<256, 256, 69632, stream>>>(xpb, wbf + 12582912, hbuf, flags + 1024,
                                     nullptr, dout, hn + 65536, cn + 65536);
}

// Round 3
// 10079.443 us; speedup vs baseline: 2.9086x; 1.2874x over previous
//
#include <hip/hip_runtime.h>
#include <stdint.h>

typedef __attribute__((ext_vector_type(8))) short short8;
typedef __attribute__((ext_vector_type(4))) float f32x4;

#define MFMA16(a, b, c) __builtin_amdgcn_mfma_f32_16x16x32_bf16((a), (b), (c), 0, 0, 0)
#define AL(p) __hip_atomic_load((p), __ATOMIC_RELAXED, __HIP_MEMORY_SCOPE_AGENT)
#define AS(p, v) __hip_atomic_store((p), (v), __ATOMIC_RELAXED, __HIP_MEMORY_SCOPE_AGENT)

__device__ __forceinline__ unsigned short f2bf(float f) {
  unsigned u = __float_as_uint(f);
  u = (u + 0x7FFFu + ((u >> 16) & 1u)) >> 16;   // RNE
  return (unsigned short)u;
}
__device__ __forceinline__ float bf2f(unsigned short u) {
  return __uint_as_float(((unsigned)u) << 16);
}

// ---------------- prep: fp32 -> bf16 conversion ----------------
__global__ void k_cvt(const float* __restrict__ src, unsigned short* __restrict__ dst, int n4) {
  int stride = gridDim.x * blockDim.x;
  for (int i = blockIdx.x * blockDim.x + threadIdx.x; i < n4; i += stride) {
    float4 v = reinterpret_cast<const float4*>(src)[i];
    ushort4 o;
    o.x = f2bf(v.x); o.y = f2bf(v.y); o.z = f2bf(v.z); o.w = f2bf(v.w);
    reinterpret_cast<ushort4*>(dst)[i] = o;
  }
}

__global__ void k_bias(const float* __restrict__ a, const float* __restrict__ b,
                       float* __restrict__ o, int n) {
  int i = blockIdx.x * blockDim.x + threadIdx.x;
  if (i < n) o[i] = a[i] + b[i];
}

// ---------------- xp GEMM: writes INTERLEAVED xp layout ----------------
// out element for (row r, gate col c): r*4096 + (jc>>1)*8 + gate*2 + (jc&1)
// where gate = c>>10, jc = c&1023.  So [i0 i1 f0 f1 g0 g1 o0 o1] per col-pair.
__global__ __launch_bounds__(256) void k_gemm(
    const unsigned short* __restrict__ A,
    const unsigned short* __restrict__ W,
    const float* __restrict__ bias,
    unsigned short* __restrict__ out,
    int mode) {
  const int tid = threadIdx.x, l = tid & 63, wv = tid >> 6;
  const int wm = wv >> 1, wn = wv & 1;
  const int tm = blockIdx.x >> 5, tn = blockIdx.x & 31;   // 256 x 32 tiles of 128x128
  const int m_base = tm * 128 + wm * 64;
  const int n_base = tn * 128 + wn * 64;
  const int lr = l & 15, k8 = (l >> 4) << 3;

  size_t a_off[4], b_off[4];
#pragma unroll
  for (int i = 0; i < 4; ++i) {
    int r = m_base + i * 16 + lr;
    int ar = mode ? r : (((r & 63) << 9) + (r >> 6));
    a_off[i] = ((size_t)ar << 10) + k8;
    int nr = n_base + i * 16 + lr;
    b_off[i] = ((size_t)nr << 10) + k8;
  }
  f32x4 acc[4][4] = {};
#pragma unroll 2
  for (int k0 = 0; k0 < 1024; k0 += 32) {
    short8 a[4], b[4];
#pragma unroll
    for (int i = 0; i < 4; ++i) a[i] = *reinterpret_cast<const short8*>(A + a_off[i] + k0);
#pragma unroll
    for (int j = 0; j < 4; ++j) b[j] = *reinterpret_cast<const short8*>(W + b_off[j] + k0);
#pragma unroll
    for (int i = 0; i < 4; ++i)
#pragma unroll
      for (int j = 0; j < 4; ++j) acc[i][j] = MFMA16(a[i], b[j], acc[i][j]);
  }
  const int oq = (l >> 4) << 2, oc = l & 15;
#pragma unroll
  for (int j = 0; j < 4; ++j) {
    int col = n_base + j * 16 + oc;
    int gate = col >> 10, jc = col & 1023;
    size_t cidx = (size_t)(((jc >> 1) << 3) + (gate << 1) + (jc & 1));
    float bs = bias[col];
#pragma unroll
    for (int i = 0; i < 4; ++i) {
      int r0 = m_base + i * 16 + oq;
#pragma unroll
      for (int q = 0; q < 4; ++q)
        out[(((size_t)(r0 + q)) << 12) + cidx] = f2bf(acc[i][j][q] + bs);
    }
  }
}

// ---------------- persistent LSTM recurrence ----------------
// grid = 256 WGs x 256 threads. Group g = wg>>7: batches [g*32, g*32+32).
// WG w (0..127) owns h-cols [8w, 8w+8) -> 32 gate cols c = gate*8+hl.
// Waves: wv = ks*2 + mt  (ks = K-half, mt = 16-row m-tile).
// W_hh fragments live in REGISTERS (constant across steps, 128 VGPR).
// Flat one-hop barrier; h exchanged via sc-bypass loads/stores (MALL-coherent).
__global__ __launch_bounds__(256, 1) void k_rec(
    const unsigned short* __restrict__ xp,     // interleaved (S*B, 4096) bf16
    const unsigned short* __restrict__ Whh,    // (4096, 1024) bf16
    unsigned short* __restrict__ hbuf,         // 2 x (64 x 1024) bf16
    int* __restrict__ flags,                   // per group at +g*256: 128 flags
    unsigned short* __restrict__ out_bf,       // layer0: (S,B,1024) bf16, else null
    float* __restrict__ out_f32,               // layer1: (B,S,1024) fp32, else null
    float* __restrict__ hn, float* __restrict__ cn) {
  __shared__ float gates[2][32][34];           // [ks][batch][gatecol], pad 34

  const int tid = threadIdx.x;
  const int l = tid & 63, wv = tid >> 6;
  const int g = blockIdx.x >> 7;
  const int w = blockIdx.x & 127;

  int* gflags = flags + (g << 8);

  const int ks = wv >> 1, mt = wv & 1;
  const int lr16 = l & 15, k8 = (l >> 4) << 3;

  // ---- B fragments -> registers (once). c = nn*16+lr16, W row = (c>>3)*1024 + 8w + (c&7)
  short8 bf0[16], bf1[16];
  {
    const size_t r0 = ((size_t)(lr16 >> 3) << 10) + (w << 3) + (lr16 & 7);
    const size_t r1 = ((size_t)(2 + (lr16 >> 3)) << 10) + (w << 3) + (lr16 & 7);
    const unsigned short* p0 = Whh + (r0 << 10) + (ks << 9) + k8;
    const unsigned short* p1 = Whh + (r1 << 10) + (ks << 9) + k8;
#pragma unroll
    for (int kk = 0; kk < 16; ++kk) {
      bf0[kk] = *reinterpret_cast<const short8*>(p0 + (kk << 5));
      bf1[kk] = *reinterpret_cast<const short8*>(p1 + (kk << 5));
    }
  }

  // a-frag base offset (within one h buffer), in ushorts
  const int arow = (g << 5) + (mt << 4) + lr16;
  const size_t aoff = ((size_t)arow << 10) + (ks << 9) + k8;

  // elementwise mapping: tid<128, 32 batches x 4 threads x 2 cols
  const bool ew = tid < 128;
  const int b_l = tid >> 2;
  const int jj2 = (tid & 3) << 1;
  const int b_g = (g << 5) + b_l;
  const int hcol = (w << 3) + jj2;
  const int jp8 = (((w << 2) + (jj2 >> 1)) << 3);   // ushort offset of uint4 in xp row

  float cs0 = 0.f, cs1 = 0.f;

  auto xload = [&](int t) -> uint4 {
    return *reinterpret_cast<const uint4*>(
        xp + (((size_t)((t << 6) + b_g)) << 12) + jp8);
  };

  auto step = [&](int t, uint4 xv) {
    if (t > 0) {
      const unsigned short* ab = hbuf + ((size_t)(t & 1) << 16) + aoff;
      short8 av[16];
#pragma unroll
      for (int kk = 0; kk < 16; ++kk) {
        const unsigned short* p = ab + (kk << 5);
        asm volatile("global_load_dwordx4 %0, %1, off sc0 sc1"
                     : "=v"(av[kk]) : "v"(p) : "memory");
      }
      asm volatile("s_waitcnt vmcnt(0)" ::: "memory");
      __builtin_amdgcn_sched_barrier(0);
      f32x4 a0 = {0.f, 0.f, 0.f, 0.f}, a1 = {0.f, 0.f, 0.f, 0.f};
#pragma unroll
      for (int kk = 0; kk < 16; ++kk) {
        a0 = MFMA16(av[kk], bf0[kk], a0);
        a1 = MFMA16(av[kk], bf1[kk], a1);
      }
      const int grow = (mt << 4) + ((l >> 4) << 2);
#pragma unroll
      for (int q = 0; q < 4; ++q) {
        gates[ks][grow + q][lr16] = a0[q];
        gates[ks][grow + q][16 + lr16] = a1[q];
      }
    }
    __syncthreads();

    if (ew) {
      float gi0 = bf2f((unsigned short)(xv.x)), gi1 = bf2f((unsigned short)(xv.x >> 16));
      float gf0 = bf2f((unsigned short)(xv.y)), gf1 = bf2f((unsigned short)(xv.y >> 16));
      float gg0 = bf2f((unsigned short)(xv.z)), gg1 = bf2f((unsigned short)(xv.z >> 16));
      float go0 = bf2f((unsigned short)(xv.w)), go1 = bf2f((unsigned short)(xv.w >> 16));
      if (t > 0) {
        // gate col for gate G, pair jj2: c = G*8 + jj2 (even -> float2 ok, stride 34*4B)
        const float* g0 = &gates[0][b_l][0];
        const float* g1 = &gates[1][b_l][0];
        float2 vi = *(const float2*)(g0 + jj2)      ; float2 wi = *(const float2*)(g1 + jj2);
        float2 vf = *(const float2*)(g0 + 8 + jj2)  ; float2 wf = *(const float2*)(g1 + 8 + jj2);
        float2 vg = *(const float2*)(g0 + 16 + jj2) ; float2 wg = *(const float2*)(g1 + 16 + jj2);
        float2 vo = *(const float2*)(g0 + 24 + jj2) ; float2 wo = *(const float2*)(g1 + 24 + jj2);
        gi0 += vi.x + wi.x; gi1 += vi.y + wi.y;
        gf0 += vf.x + wf.x; gf1 += vf.y + wf.y;
        gg0 += vg.x + wg.x; gg1 += vg.y + wg.y;
        go0 += vo.x + wo.x; go1 += vo.y + wo.y;
      }
      float i0 = 1.f / (1.f + __expf(-gi0)), i1 = 1.f / (1.f + __expf(-gi1));
      float f0 = 1.f / (1.f + __expf(-gf0)), f1 = 1.f / (1.f + __expf(-gf1));
      float g0v = tanhf(gg0), g1v = tanhf(gg1);
      float o0 = 1.f / (1.f + __expf(-go0)), o1 = 1.f / (1.f + __expf(-go1));
      cs0 = f0 * cs0 + i0 * g0v;
      cs1 = f1 * cs1 + i1 * g1v;
      float h0v = o0 * tanhf(cs0);
      float h1v = o1 * tanhf(cs1);
      unsigned hw = (unsigned)f2bf(h0v) | ((unsigned)f2bf(h1v) << 16);

      AS(reinterpret_cast<unsigned*>(
             hbuf + ((size_t)((t + 1) & 1) << 16) + ((size_t)b_g << 10) + hcol), hw);
      if (out_bf) {
        *reinterpret_cast<unsigned*>(
            out_bf + ((((size_t)t << 6) + b_g) << 10) + hcol) = hw;
      } else {
        *reinterpret_cast<float2*>(
            out_f32 + ((((size_t)b_g << 9) + t) << 10) + hcol) = make_float2(h0v, h1v);
      }
      if (t == 511) {
        *reinterpret_cast<float2*>(hn + ((size_t)b_g << 10) + hcol) = make_float2(h0v, h1v);
        *reinterpret_cast<float2*>(cn + ((size_t)b_g << 10) + hcol) = make_float2(cs0, cs1);
      }
    }

    // ---- flat one-hop barrier ----
    if (t != 511) {
      asm volatile("s_waitcnt vmcnt(0)" ::: "memory");
      __syncthreads();
      if (wv == 0) {
        if (l == 0) AS(&gflags[w], t + 1);
        for (;;) {
          int f0 = AL(&gflags[l << 1]);
          int f1 = AL(&gflags[(l << 1) + 1]);
          if (__all((f0 > t) && (f1 > t))) break;
          __builtin_amdgcn_s_sleep(1);
        }
      }
      __syncthreads();
    }
  };

  // ---- main loop: 8-step superchunks, xp double-buffer prefetch ----
  uint4 zz = {0u, 0u, 0u, 0u};
  uint4 xA[4] = {zz, zz, zz, zz}, xB[4] = {zz, zz, zz, zz};
  if (ew) {
#pragma unroll
    for (int s = 0; s < 4; ++s) xA[s] = xload(s);
  }
  for (int tc = 0; tc < 512; tc += 8) {
    if (ew) {
#pragma unroll
      for (int s = 0; s < 4; ++s) xB[s] = xload(tc + 4 + s);
    }
#pragma unroll
    for (int s = 0; s < 4; ++s) step(tc + s, xA[s]);
    if (tc + 8 < 512 && ew) {
#pragma unroll
      for (int s = 0; s < 4; ++s) xA[s] = xload(tc + 8 + s);
    }
#pragma unroll
    for (int s = 0; s < 4; ++s) step(tc + 4 + s, xB[s]);
  }
}

// ---------------- launch ----------------
extern "C" void kernel_launch(void* const* d_in, const int* in_sizes, int n_in,
                              void* d_out, int out_size, void* d_ws, size_t ws_size,
                              hipStream_t stream) {
  (void)in_sizes; (void)n_in; (void)out_size; (void)ws_size;
  const float* x    = (const float*)d_in[0];
  const float* Wih0 = (const float*)d_in[1];
  const float* bih0 = (const float*)d_in[2];
  const float* Whh0 = (const float*)d_in[3];
  const float* bhh0 = (const float*)d_in[4];
  const float* Wih1 = (const float*)d_in[5];
  const float* bih1 = (const float*)d_in[6];
  const float* Whh1 = (const float*)d_in[7];
  const float* bhh1 = (const float*)d_in[8];
  float* dout = (float*)d_out;

  char* ws = (char*)d_ws;
  int*            flags = (int*)ws;                          // 8 KB
  unsigned short* hbuf  = (unsigned short*)(ws + 8192);      // 256 KB
  float*          bias0 = (float*)(ws + 270336);             // 16 KB
  float*          bias1 = (float*)(ws + 286720);             // 16 KB
  unsigned short* wbf   = (unsigned short*)(ws + 303104);    // 32 MB: ih0,hh0,ih1,hh1
  unsigned short* xbf   = wbf + 16777216;                    // 64 MB
  unsigned short* out0  = xbf + 33554432;                    // 64 MB
  unsigned short* xpb   = out0 + 33554432;                   // 256 MB (shared both layers)

  hipMemsetAsync(flags, 0, 8192, stream);

  k_cvt<<<1024, 256, 0, stream>>>(x, xbf, 33554432 / 4);
  k_cvt<<<256, 256, 0, stream>>>(Wih0, wbf + 0,        4194304 / 4);
  k_cvt<<<256, 256, 0, stream>>>(Whh0, wbf + 4194304,  4194304 / 4);
  k_cvt<<<256, 256, 0, stream>>>(Wih1, wbf + 8388608,  4194304 / 4);
  k_cvt<<<256, 256, 0, stream>>>(Whh1, wbf + 12582912, 4194304 / 4);
  k_bias<<<16, 256, 0, stream>>>(bih0, bhh0, bias0, 4096);
  k_bias<<<16, 256, 0, stream>>>(bih1, bhh1, bias1, 4096);

  float* hn = dout + 33554432;
  float* cn = dout + 33554432 + 131072;

  // layer 0
  k_gemm<<<8192, 256, 0, stream>>>(xbf, wbf + 0, bias0, xpb, 0);
  k_rec<<<256, 256, 0, stream>>>(xpb, wbf + 4194304, hbuf, flags,
                                 out0, nullptr, hn, cn);
  // layer 1
  k_gemm<<<8192, 256, 0, stream>>>(out0, wbf + 8388608, bias1, xpb, 1);
  k_rec<<<256, 256, 0, stream>>>(xpb, wbf + 12582912, hbuf, flags + 1024,
                                 nullptr, dout, hn + 65536, cn + 65536);
}

// Round 4
// 7848.006 us; speedup vs baseline: 3.7356x; 1.2843x over previous
//
#include <hip/hip_runtime.h>
#include <stdint.h>

typedef __attribute__((ext_vector_type(8))) short short8;
typedef __attribute__((ext_vector_type(4))) float f32x4;

#define MFMA16(a, b, c) __builtin_amdgcn_mfma_f32_16x16x32_bf16((a), (b), (c), 0, 0, 0)
#define AL(p) __hip_atomic_load((p), __ATOMIC_RELAXED, __HIP_MEMORY_SCOPE_AGENT)
#define AS(p, v) __hip_atomic_store((p), (v), __ATOMIC_RELAXED, __HIP_MEMORY_SCOPE_AGENT)

__device__ __forceinline__ unsigned short f2bf(float f) {
  unsigned u = __float_as_uint(f);
  u = (u + 0x7FFFu + ((u >> 16) & 1u)) >> 16;   // RNE
  return (unsigned short)u;
}
__device__ __forceinline__ float bf2f(unsigned short u) {
  return __uint_as_float(((unsigned)u) << 16);
}

// ---------------- prep: fp32 -> bf16 conversion ----------------
__global__ void k_cvt(const float* __restrict__ src, unsigned short* __restrict__ dst, int n4) {
  int stride = gridDim.x * blockDim.x;
  for (int i = blockIdx.x * blockDim.x + threadIdx.x; i < n4; i += stride) {
    float4 v = reinterpret_cast<const float4*>(src)[i];
    ushort4 o;
    o.x = f2bf(v.x); o.y = f2bf(v.y); o.z = f2bf(v.z); o.w = f2bf(v.w);
    reinterpret_cast<ushort4*>(dst)[i] = o;
  }
}

__global__ void k_bias(const float* __restrict__ a, const float* __restrict__ b,
                       float* __restrict__ o, int n) {
  int i = blockIdx.x * blockDim.x + threadIdx.x;
  if (i < n) o[i] = a[i] + b[i];
}

// ---------------- xp GEMM: writes per-column interleaved xp layout ----------------
// out element for (row r, gate col c): r*4096 + jc*4 + gate   (jc = c&1023, gate = c>>10)
// i.e. [i f g o] contiguous per h-column.
__global__ __launch_bounds__(256) void k_gemm(
    const unsigned short* __restrict__ A,
    const unsigned short* __restrict__ W,
    const float* __restrict__ bias,
    unsigned short* __restrict__ out,
    int mode) {
  const int tid = threadIdx.x, l = tid & 63, wv = tid >> 6;
  const int wm = wv >> 1, wn = wv & 1;
  const int tm = blockIdx.x >> 5, tn = blockIdx.x & 31;   // 256 x 32 tiles of 128x128
  const int m_base = tm * 128 + wm * 64;
  const int n_base = tn * 128 + wn * 64;
  const int lr = l & 15, k8 = (l >> 4) << 3;

  size_t a_off[4], b_off[4];
#pragma unroll
  for (int i = 0; i < 4; ++i) {
    int r = m_base + i * 16 + lr;
    int ar = mode ? r : (((r & 63) << 9) + (r >> 6));
    a_off[i] = ((size_t)ar << 10) + k8;
    int nr = n_base + i * 16 + lr;
    b_off[i] = ((size_t)nr << 10) + k8;
  }
  f32x4 acc[4][4] = {};
#pragma unroll 2
  for (int k0 = 0; k0 < 1024; k0 += 32) {
    short8 a[4], b[4];
#pragma unroll
    for (int i = 0; i < 4; ++i) a[i] = *reinterpret_cast<const short8*>(A + a_off[i] + k0);
#pragma unroll
    for (int j = 0; j < 4; ++j) b[j] = *reinterpret_cast<const short8*>(W + b_off[j] + k0);
#pragma unroll
    for (int i = 0; i < 4; ++i)
#pragma unroll
      for (int j = 0; j < 4; ++j) acc[i][j] = MFMA16(a[i], b[j], acc[i][j]);
  }
  const int oq = (l >> 4) << 2, oc = l & 15;
#pragma unroll
  for (int j = 0; j < 4; ++j) {
    int col = n_base + j * 16 + oc;
    int gate = col >> 10, jc = col & 1023;
    size_t cidx = (size_t)((jc << 2) + gate);
    float bs = bias[col];
#pragma unroll
    for (int i = 0; i < 4; ++i) {
      int r0 = m_base + i * 16 + oq;
#pragma unroll
      for (int q = 0; q < 4; ++q)
        out[(((size_t)(r0 + q)) << 12) + cidx] = f2bf(acc[i][j][q] + bs);
    }
  }
}

// ---------------- persistent LSTM recurrence ----------------
// grid = 256 WGs x 512 threads. Group g = wg>>6: batches [16g, 16g+16).
// WG w (0..63) owns h-cols [16w, 16w+16) -> 64 gate cols (nn=gate, j=0..15).
// Wave ks (0..7) covers K slice [128ks, 128ks+128): zero read duplication
// (32 KB h-read per WG per step; 8 MB/step chip-wide, half of R3).
// W_hh frags register-resident (64 VGPR). Split-K partials reduced via LDS.
__global__ __launch_bounds__(512, 2) void k_rec(
    const unsigned short* __restrict__ xp,     // col-interleaved (S*B, 4096) bf16
    const unsigned short* __restrict__ Whh,    // (4096, 1024) bf16
    unsigned short* __restrict__ hbuf,         // 2 x (64 x 1024) bf16
    int* __restrict__ flags,                   // per group at +g*64: 64 flags
    unsigned short* __restrict__ out_bf,       // layer0: (S,B,1024) bf16, else null
    float* __restrict__ out_f32,               // layer1: (B,S,1024) fp32, else null
    float* __restrict__ hn, float* __restrict__ cn) {
  // part[b][nn][j][ks] with ks-stride padded to 10 words (bank spread)
  __shared__ float part[16 * 4 * 16 * 10];     // 40 KB

  const int tid = threadIdx.x;
  const int l = tid & 63, ks = tid >> 6;       // 8 waves = 8 K-slices
  const int g = blockIdx.x >> 6;
  const int w = blockIdx.x & 63;

  int* gflags = flags + (g << 6);

  const int lr16 = l & 15, k8 = (l >> 4) << 3;

  // ---- B fragments -> registers (once): bf[nn][kk]
  // W row R = nn*1024 + 16w + lr16, col = ks*128 + kk*32 + k8
  short8 bf[4][4];
#pragma unroll
  for (int nn = 0; nn < 4; ++nn) {
    const unsigned short* wp =
        Whh + (((size_t)nn << 10) + (w << 4) + lr16) * 1024 + (ks << 7) + k8;
#pragma unroll
    for (int kk = 0; kk < 4; ++kk)
      bf[nn][kk] = *reinterpret_cast<const short8*>(wp + (kk << 5));
  }

  // a-frag base offset (within one h buffer), in ushorts
  const int arow = (g << 4) + lr16;
  const size_t aoff = ((size_t)arow << 10) + (ks << 7) + k8;

  // elementwise mapping: tid<256 -> (batch b_l, col j)
  const bool ew = tid < 256;
  const int b_l = (tid >> 4) & 15;
  const int j = tid & 15;
  const int b_g = (g << 4) + b_l;
  const int hcol = (w << 4) + j;

  float cs = 0.f;

  auto xload = [&](int t) -> uint2 {
    return *reinterpret_cast<const uint2*>(
        xp + (((size_t)((t << 6) + b_g)) << 12) + (hcol << 2));
  };

  auto step = [&](int t, uint2 xv) {
    if (t > 0) {
      const unsigned short* ab = hbuf + ((size_t)(t & 1) << 16) + aoff;
      short8 av[4];
#pragma unroll
      for (int kk = 0; kk < 4; ++kk) {
        const unsigned short* p = ab + (kk << 5);
        asm volatile("global_load_dwordx4 %0, %1, off sc0 sc1"
                     : "=v"(av[kk]) : "v"(p) : "memory");
      }
      asm volatile("s_waitcnt vmcnt(0)" ::: "memory");
      __builtin_amdgcn_sched_barrier(0);
      f32x4 acc[4] = {{0.f,0.f,0.f,0.f},{0.f,0.f,0.f,0.f},{0.f,0.f,0.f,0.f},{0.f,0.f,0.f,0.f}};
#pragma unroll
      for (int kk = 0; kk < 4; ++kk)
#pragma unroll
        for (int nn = 0; nn < 4; ++nn)
          acc[nn] = MFMA16(av[kk], bf[nn][kk], acc[nn]);
      // write partials: D col=lane&15 (=j), row=(lane>>4)*4+q (=batch)
#pragma unroll
      for (int nn = 0; nn < 4; ++nn)
#pragma unroll
        for (int q = 0; q < 4; ++q) {
          int b = ((l >> 4) << 2) + q;
          part[(((b << 2) + nn) << 4 | lr16) * 10 + ks] = acc[nn][q];
        }
    }
    __syncthreads();

    if (ew) {
      float gi = bf2f((unsigned short)(xv.x)), gf = bf2f((unsigned short)(xv.x >> 16));
      float gg = bf2f((unsigned short)(xv.y)), go = bf2f((unsigned short)(xv.y >> 16));
      if (t > 0) {
        const int pb = ((b_l << 2) << 4 | j) * 10;   // gate stride = 16*10 words
        float si = 0.f, sf = 0.f, sg = 0.f, so = 0.f;
#pragma unroll
        for (int kk = 0; kk < 8; ++kk) {
          si += part[pb + kk];
          sf += part[pb + 160 + kk];
          sg += part[pb + 320 + kk];
          so += part[pb + 480 + kk];
        }
        gi += si; gf += sf; gg += sg; go += so;
      }
      float iv = 1.f / (1.f + __expf(-gi));
      float fv = 1.f / (1.f + __expf(-gf));
      float gv = tanhf(gg);
      float ov = 1.f / (1.f + __expf(-go));
      cs = fv * cs + iv * gv;
      float hv = ov * tanhf(cs);
      unsigned short h16 = f2bf(hv);

      AS(hbuf + ((size_t)((t + 1) & 1) << 16) + ((size_t)b_g << 10) + hcol, h16);
      if (out_bf) {
        out_bf[((((size_t)t << 6) + b_g) << 10) + hcol] = h16;
      } else {
        out_f32[((((size_t)b_g << 9) + t) << 10) + hcol] = hv;
      }
      if (t == 511) {
        hn[((size_t)b_g << 10) + hcol] = hv;
        cn[((size_t)b_g << 10) + hcol] = cs;
      }
    }

    // ---- group barrier: drain own stores, arrive, all-poll (64 flags, 1/lane) ----
    if (t != 511) {
      asm volatile("s_waitcnt vmcnt(0)" ::: "memory");
      __syncthreads();
      if (tid == 0) AS(&gflags[w], t + 1);
      if (ks == 0) {
        for (;;) {
          int f = AL(&gflags[l]);
          if (__all(f > t)) break;
          __builtin_amdgcn_s_sleep(1);
        }
      }
      __syncthreads();
    }
  };

  // ---- main loop: 8-step superchunks, xp double-buffer prefetch ----
  uint2 zz = {0u, 0u};
  uint2 xA[4] = {zz, zz, zz, zz}, xB[4] = {zz, zz, zz, zz};
  if (ew) {
#pragma unroll
    for (int s = 0; s < 4; ++s) xA[s] = xload(s);
  }
  for (int tc = 0; tc < 512; tc += 8) {
    if (ew) {
#pragma unroll
      for (int s = 0; s < 4; ++s) xB[s] = xload(tc + 4 + s);
    }
#pragma unroll
    for (int s = 0; s < 4; ++s) step(tc + s, xA[s]);
    if (tc + 8 < 512 && ew) {
#pragma unroll
      for (int s = 0; s < 4; ++s) xA[s] = xload(tc + 8 + s);
    }
#pragma unroll
    for (int s = 0; s < 4; ++s) step(tc + 4 + s, xB[s]);
  }
}

// ---------------- launch ----------------
extern "C" void kernel_launch(void* const* d_in, const int* in_sizes, int n_in,
                              void* d_out, int out_size, void* d_ws, size_t ws_size,
                              hipStream_t stream) {
  (void)in_sizes; (void)n_in; (void)out_size; (void)ws_size;
  const float* x    = (const float*)d_in[0];
  const float* Wih0 = (const float*)d_in[1];
  const float* bih0 = (const float*)d_in[2];
  const float* Whh0 = (const float*)d_in[3];
  const float* bhh0 = (const float*)d_in[4];
  const float* Wih1 = (const float*)d_in[5];
  const float* bih1 = (const float*)d_in[6];
  const float* Whh1 = (const float*)d_in[7];
  const float* bhh1 = (const float*)d_in[8];
  float* dout = (float*)d_out;

  char* ws = (char*)d_ws;
  int*            flags = (int*)ws;                          // 8 KB
  unsigned short* hbuf  = (unsigned short*)(ws + 8192);      // 256 KB
  float*          bias0 = (float*)(ws + 270336);             // 16 KB
  float*          bias1 = (float*)(ws + 286720);             // 16 KB
  unsigned short* wbf   = (unsigned short*)(ws + 303104);    // 32 MB: ih0,hh0,ih1,hh1
  unsigned short* xbf   = wbf + 16777216;                    // 64 MB
  unsigned short* out0  = xbf + 33554432;                    // 64 MB
  unsigned short* xpb   = out0 + 33554432;                   // 256 MB (shared both layers)

  hipMemsetAsync(flags, 0, 8192, stream);

  k_cvt<<<1024, 256, 0, stream>>>(x, xbf, 33554432 / 4);
  k_cvt<<<256, 256, 0, stream>>>(Wih0, wbf + 0,        4194304 / 4);
  k_cvt<<<256, 256, 0, stream>>>(Whh0, wbf + 4194304,  4194304 / 4);
  k_cvt<<<256, 256, 0, stream>>>(Wih1, wbf + 8388608,  4194304 / 4);
  k_cvt<<<256, 256, 0, stream>>>(Whh1, wbf + 12582912, 4194304 / 4);
  k_bias<<<16, 256, 0, stream>>>(bih0, bhh0, bias0, 4096);
  k_bias<<<16, 256, 0, stream>>>(bih1, bhh1, bias1, 4096);

  float* hn = dout + 33554432;
  float* cn = dout + 33554432 + 131072;

  // layer 0
  k_gemm<<<8192, 256, 0, stream>>>(xbf, wbf + 0, bias0, xpb, 0);
  k_rec<<<256, 512, 0, stream>>>(xpb, wbf + 4194304, hbuf, flags,
                                 out0, nullptr, hn, cn);
  // layer 1
  k_gemm<<<8192, 256, 0, stream>>>(out0, wbf + 8388608, bias1, xpb, 1);
  k_rec<<<256, 512, 0, stream>>>(xpb, wbf + 12582912, hbuf, flags + 1024,
                                 nullptr, dout, hn + 65536, cn + 65536);
}